// Round 7
// baseline (1159.071 us; speedup 1.0000x reference)
//
#include <hip/hip_runtime.h>

#define NT 20        // time steps
#define BT 4096      // batch
#define HD 128       // hidden
#define RT 81920     // total rows = K*B = 20*4096
#define RB 64        // rows per block

typedef _Float16 half8 __attribute__((ext_vector_type(8)));
typedef _Float16 half2v __attribute__((ext_vector_type(2)));
typedef float f32x4 __attribute__((ext_vector_type(4)));
typedef float f32x2 __attribute__((ext_vector_type(2)));
typedef unsigned u32x4 __attribute__((ext_vector_type(4)));

#if defined(__has_builtin)
#  if __has_builtin(__builtin_amdgcn_fdot2)
#    define HAVE_FDOT2 1
#  endif
#endif

__device__ __forceinline__ float hsig(float x) {
  return fminf(fmaxf(x * 0.16666667f + 0.5f, 0.0f), 1.0f);
}
__device__ __forceinline__ float htanh(float x) {
  return fminf(fmaxf(x, -1.0f), 1.0f);
}

__device__ __forceinline__ float dot2(half2v a, half2v b, float c) {
#ifdef HAVE_FDOT2
  return __builtin_amdgcn_fdot2(a, b, c, false);
#else
  return fmaf((float)a[0], (float)b[0], fmaf((float)a[1], (float)b[1], c));
#endif
}

__device__ __forceinline__ half8 ldcvt8(const float* __restrict__ p) {
  f32x4 a = *(const f32x4*)p;
  f32x4 b = *(const f32x4*)(p + 4);
  half8 r;
  r[0] = (_Float16)a[0]; r[1] = (_Float16)a[1];
  r[2] = (_Float16)a[2]; r[3] = (_Float16)a[3];
  r[4] = (_Float16)b[0]; r[5] = (_Float16)b[1];
  r[6] = (_Float16)b[2]; r[7] = (_Float16)b[3];
  return r;
}

__device__ __forceinline__ half8 augA(unsigned xv, int lg) {
  unsigned u0 = (lg == 0) ? xv : 0u;
  unsigned u1 = (lg == 0) ? 0x00003C00u : 0u;  // f16 1.0 in elem 2
  u32x4 xu = {u0, u1, 0u, 0u};
  return __builtin_bit_cast(half8, xu);
}

// Persistent LSTM decoder. 4 waves (256 thr), RB=64 rows, (256,2).
// R1/R3/R5/R6 all land ~420us regardless of spill/occupancy => stall is
// barrier-lockstep phase alignment. R7 desyncs with IDENTICAL numerics:
//  1. wave-rotated m-tile order mm=(w+1+j)&3 (fold at j=3, all waves)
//  2. a-frag prefetch pipeline A[2][5]: tile j+1's ds_reads issue before
//     tile j's MFMA cluster -> 1 exposed LDS latency/step instead of 4
//  3. cst in LDS [mm][nj][tid]*16B (contiguous-16B b128) frees 32 regs
//     for the prefetch set: est ~210 arch + 32 acc <= 256 budget.
__global__ __launch_bounds__(256, 2) void decoder_kernel(
    const float* __restrict__ obs, const float* __restrict__ pred,
    const float* __restrict__ Wm1, const float* __restrict__ bm1,
    const float* __restrict__ Wm2, const float* __restrict__ bm2,
    const float* __restrict__ W_ih, const float* __restrict__ W_hh,
    const float* __restrict__ b_ih, const float* __restrict__ b_hh,
    const float* __restrict__ W_out, const float* __restrict__ b_out,
    float* __restrict__ outp)
{
  __shared__ __align__(16) char lds[71168];
  const int tid = threadIdx.x;
  const int w   = tid >> 6;       // wave id 0..3
  const int l   = tid & 63;
  const int l15 = l & 15;
  const int lg  = l >> 4;         // lane group 0..3
  const int r0  = blockIdx.x * RB;
  const int b0  = r0 & (BT - 1);

  char* const buf0 = lds;             // h buffer parity 0 (16KB)
  char* const h1l  = lds + 16384;     // parity-1 h buffer; aliases MLP mid acts
  char* const cstl = lds + 32768;     // c state: [mm][nj][tid] f32x4 (32KB)
  char* const obsl = lds + 65536;     // obs staged: [20][64] packed f16x2 (5KB)
  char* const wol  = lds + 70656;     // W_out f16 [2][128] (512B)

  const f32x4 fzero = {0.f, 0.f, 0.f, 0.f};

  const int rdmask = (l15 & 7) << 4;
  const int arow  = l15 * 256;              // A-read row byte
  const int base0 = (16 * lg) ^ rdmask;     // A-read k byte; ao[kt]=(64*kt)^base0
  const int wcol2 = 64 * w + 2 * l15;       // h-write col byte (pre-swizzle), +32*nj
  const int cb    = tid * 16;               // + (2*mm+nj)*4096 in cstl

  // ---- stage W_out (f16), obs (packed f16x2), zero c-state ----
  ((_Float16*)wol)[tid] = (_Float16)W_out[tid];
  for (int i = tid; i < NT * RB; i += 256) {
    int t = i >> 6, row = i & 63;
    int tp = (t > 0) ? t - 1 : 0;
    f32x2 xv = *(const f32x2*)(obs + ((size_t)tp * BT + b0 + row) * 2);
    half2v hp; hp[0] = (_Float16)xv[0]; hp[1] = (_Float16)xv[1];
    *(unsigned*)(obsl + (size_t)i * 4) = __builtin_bit_cast(unsigned, hp);
  }
#pragma unroll
  for (int s = 0; s < 8; ++s)
    *(f32x4*)(cstl + s * 4096 + cb) = fzero;

  // ---------------- Prologue: h0 = MLP(pred) ----------------
  {
    half8 a1[4], b1[4][4];
#pragma unroll
    for (int kt = 0; kt < 4; ++kt)
      a1[kt] = ldcvt8(pred + (size_t)(r0 + 16 * w + l15) * HD + kt * 32 + lg * 8);
#pragma unroll
    for (int n = 0; n < 4; ++n)
#pragma unroll
      for (int kt = 0; kt < 4; ++kt)
        b1[n][kt] = ldcvt8(Wm1 + (l15 + 16 * n) * HD + kt * 32 + lg * 8);
    f32x4 acc1[4] = {fzero, fzero, fzero, fzero};
#pragma unroll
    for (int kt = 0; kt < 4; ++kt)
#pragma unroll
      for (int n = 0; n < 4; ++n)
        acc1[n] = __builtin_amdgcn_mfma_f32_16x16x32_f16(a1[kt], b1[n][kt], acc1[n], 0, 0, 0);
#pragma unroll
    for (int n = 0; n < 4; ++n) {
      int c = l15 + 16 * n;
      float bb = bm1[c];
#pragma unroll
      for (int reg = 0; reg < 4; ++reg) {
        int row = 16 * w + 4 * lg + reg;
        float v = acc1[n][reg] + bb;
        v = v >= 0.f ? v : 0.01f * v;
        *(_Float16*)(h1l + row * 128 + ((2 * c) ^ ((row & 7) << 4))) = (_Float16)v;
      }
    }
  }
  __syncthreads();
  {
    half8 a2[2], b2[8][2];
#pragma unroll
    for (int kt = 0; kt < 2; ++kt)
      a2[kt] = *(const half8*)(h1l + (16 * w + l15) * 128 + ((64 * kt + 16 * lg) ^ rdmask));
#pragma unroll
    for (int n = 0; n < 8; ++n)
#pragma unroll
      for (int kt = 0; kt < 2; ++kt)
        b2[n][kt] = ldcvt8(Wm2 + (l15 + 16 * n) * 64 + kt * 32 + lg * 8);
    f32x4 acc2[8];
#pragma unroll
    for (int n = 0; n < 8; ++n) acc2[n] = fzero;
#pragma unroll
    for (int kt = 0; kt < 2; ++kt)
#pragma unroll
      for (int n = 0; n < 8; ++n)
        acc2[n] = __builtin_amdgcn_mfma_f32_16x16x32_f16(a2[kt], b2[n][kt], acc2[n], 0, 0, 0);
#pragma unroll
    for (int n = 0; n < 8; ++n) {
      int c = l15 + 16 * n;
      float bb = bm2[c];
#pragma unroll
      for (int reg = 0; reg < 4; ++reg) {
        int row = 16 * w + 4 * lg + reg;
        float v = acc2[n][reg] + bb;
        *(_Float16*)(buf0 + row * 256 + ((2 * c) ^ ((row & 7) << 4))) = (_Float16)v;
      }
    }
  }

  // ---- steady-state per-wave constants ----
  half8 bW[4][2][4];
  unsigned awp[4][2], abp[4][2];
#pragma unroll
  for (int gate = 0; gate < 4; ++gate)
#pragma unroll
    for (int nj = 0; nj < 2; ++nj) {
      int g = 128 * gate + 32 * w + 16 * nj + l15;
#pragma unroll
      for (int kt = 0; kt < 4; ++kt)
        bW[gate][nj][kt] = ldcvt8(W_hh + (size_t)g * HD + kt * 32 + lg * 8);
      half2v t2;
      t2[0] = (_Float16)W_ih[g * 2 + 0];
      t2[1] = (_Float16)W_ih[g * 2 + 1];
      awp[gate][nj] = __builtin_bit_cast(unsigned, t2);
      half2v t3;
      t3[0] = (_Float16)(b_ih[g] + b_hh[g]);
      t3[1] = (_Float16)0.0f;
      abp[gate][nj] = __builtin_bit_cast(unsigned, t3);
    }
  const float bo0 = b_out[0], bo1 = b_out[1];

  __syncthreads();  // h0/obs/wol/cst visible; h1l reads done

  // ---------------- 20 recurrent steps ----------------
  for (int t = 0; t < NT; ++t) {
    char* const brd = lds + ((t & 1) << 14);
    char* const bwr = lds + (((t & 1) ^ 1) << 14);

    half8 A[2][5];
    {
      const int mm0 = (w + 1) & 3;
#pragma unroll
      for (int kt = 0; kt < 4; ++kt)
        A[0][kt] = *(const half8*)(brd + mm0 * 4096 + arow + ((64 * kt) ^ base0));
      unsigned xv = *(const unsigned*)(obsl + ((t << 6) + (mm0 << 4) + l15) * 4);
      A[0][4] = augA(xv, lg);
    }

#pragma unroll
    for (int j = 0; j < 4; ++j) {
      const int mm  = (w + 1 + j) & 3;
      const int cur = j & 1;

      // c-state reads issued early (2 slots: nj=0,1)
      f32x4 cc0 = *(const f32x4*)(cstl + (2 * mm + 0) * 4096 + cb);
      f32x4 cc1 = *(const f32x4*)(cstl + (2 * mm + 1) * 4096 + cb);

      // prefetch next tile BEFORE this tile's MFMA cluster
      if (j < 3) {
        const int mn = (w + 2 + j) & 3;
#pragma unroll
        for (int kt = 0; kt < 4; ++kt)
          A[cur ^ 1][kt] = *(const half8*)(brd + mn * 4096 + arow + ((64 * kt) ^ base0));
        unsigned xv = *(const unsigned*)(obsl + ((t << 6) + (mn << 4) + l15) * 4);
        A[cur ^ 1][4] = augA(xv, lg);
      }

      f32x4 acc[4][2];
#pragma unroll
      for (int gate = 0; gate < 4; ++gate)
#pragma unroll
        for (int nj = 0; nj < 2; ++nj) acc[gate][nj] = fzero;

      __builtin_amdgcn_s_setprio(1);
#pragma unroll
      for (int kt = 0; kt < 5; ++kt) {
#pragma unroll
        for (int gate = 0; gate < 4; ++gate)
#pragma unroll
          for (int nj = 0; nj < 2; ++nj) {
            half8 bfrag;
            if (kt < 4) {
              bfrag = bW[gate][nj][kt];
            } else {
              unsigned v0 = (lg == 0) ? awp[gate][nj] : 0u;
              unsigned v1 = (lg == 0) ? abp[gate][nj] : 0u;
              u32x4 bu = {v0, v1, 0u, 0u};
              bfrag = __builtin_bit_cast(half8, bu);
            }
            acc[gate][nj] = __builtin_amdgcn_mfma_f32_16x16x32_f16(A[cur][kt], bfrag, acc[gate][nj], 0, 0, 0);
          }
      }
      __builtin_amdgcn_s_setprio(0);

      // fold: j==3 <=> mm==w; out[t-1] = h(t-1)[tile w rows] @ W_out^T
      if (j == 3 && t > 0) {
        float p0 = 0.f, p1 = 0.f;
#pragma unroll
        for (int kt = 0; kt < 4; ++kt) {
          const half8 a = A[cur][kt];
          const half8 wf0 = *(const half8*)(wol + 0   + kt * 64 + lg * 16);
          const half8 wf1 = *(const half8*)(wol + 256 + kt * 64 + lg * 16);
#pragma unroll
          for (int pp = 0; pp < 4; ++pp) {
            half2v ha; ha[0] = a[2 * pp]; ha[1] = a[2 * pp + 1];
            half2v wa; wa[0] = wf0[2 * pp]; wa[1] = wf0[2 * pp + 1];
            half2v wb; wb[0] = wf1[2 * pp]; wb[1] = wf1[2 * pp + 1];
            p0 = dot2(ha, wa, p0);
            p1 = dot2(ha, wb, p1);
          }
        }
        p0 += __shfl_xor(p0, 16, 64); p0 += __shfl_xor(p0, 32, 64);
        p1 += __shfl_xor(p1, 16, 64); p1 += __shfl_xor(p1, 32, 64);
        if (l < 16) {
          f32x2 v; v[0] = p0 + bo0; v[1] = p1 + bo1;
          *(f32x2*)(outp + (size_t)(t - 1) * (RT * 2) + (size_t)(r0 + 16 * w + l) * 2) = v;
        }
      }

      // fused LSTM update (lane-local); nj unrolled with distinct cc regs
#pragma unroll
      for (int nj = 0; nj < 2; ++nj) {
        f32x4 cn4;
#pragma unroll
        for (int reg = 0; reg < 4; ++reg) {
          float cprev = (nj == 0) ? cc0[reg] : cc1[reg];
          float cn = hsig(acc[1][nj][reg]) * cprev +
                     hsig(acc[0][nj][reg]) * htanh(acc[2][nj][reg]);
          cn4[reg] = cn;
          float hn = hsig(acc[3][nj][reg]) * htanh(cn);
          int rr = 4 * lg + reg;
          int wb = rr * 256 + ((wcol2 + 32 * nj) ^ ((rr & 7) << 4));
          *(_Float16*)(bwr + mm * 4096 + wb) = (_Float16)hn;
        }
        *(f32x4*)(cstl + (2 * mm + nj) * 4096 + cb) = cn4;
      }
    }
    __syncthreads();
  }

  // ---------------- epilogue: out[19] from h(20) (buf parity 0) ----------------
  {
    float p0 = 0.f, p1 = 0.f;
#pragma unroll
    for (int kt = 0; kt < 4; ++kt) {
      half8 a = *(const half8*)(buf0 + w * 4096 + arow + ((64 * kt) ^ base0));
      const half8 wf0 = *(const half8*)(wol + 0   + kt * 64 + lg * 16);
      const half8 wf1 = *(const half8*)(wol + 256 + kt * 64 + lg * 16);
#pragma unroll
      for (int pp = 0; pp < 4; ++pp) {
        half2v ha; ha[0] = a[2 * pp]; ha[1] = a[2 * pp + 1];
        half2v wa; wa[0] = wf0[2 * pp]; wa[1] = wf0[2 * pp + 1];
        half2v wb; wb[0] = wf1[2 * pp]; wb[1] = wf1[2 * pp + 1];
        p0 = dot2(ha, wa, p0);
        p1 = dot2(ha, wb, p1);
      }
    }
    p0 += __shfl_xor(p0, 16, 64); p0 += __shfl_xor(p0, 32, 64);
    p1 += __shfl_xor(p1, 16, 64); p1 += __shfl_xor(p1, 32, 64);
    if (l < 16) {
      f32x2 v; v[0] = p0 + bo0; v[1] = p1 + bo1;
      *(f32x2*)(outp + (size_t)19 * (RT * 2) + (size_t)(r0 + 16 * w + l) * 2) = v;
    }
  }
}

extern "C" void kernel_launch(void* const* d_in, const int* in_sizes, int n_in,
                              void* d_out, int out_size, void* d_ws, size_t ws_size,
                              hipStream_t stream) {
  const float* obs   = (const float*)d_in[0];
  const float* pred  = (const float*)d_in[1];
  const float* Wm1   = (const float*)d_in[2];
  const float* bm1   = (const float*)d_in[3];
  const float* Wm2   = (const float*)d_in[4];
  const float* bm2   = (const float*)d_in[5];
  const float* W_ih  = (const float*)d_in[6];
  const float* W_hh  = (const float*)d_in[7];
  const float* b_ih  = (const float*)d_in[8];
  const float* b_hh  = (const float*)d_in[9];
  const float* W_out = (const float*)d_in[10];
  const float* b_out = (const float*)d_in[11];

  decoder_kernel<<<RT / RB, 256, 0, stream>>>(
      obs, pred, Wm1, bm1, Wm2, bm2, W_ih, W_hh, b_ih, b_hh, W_out, b_out,
      (float*)d_out);
}

// Round 8
// 318.390 us; speedup vs baseline: 3.6404x; 3.6404x over previous
//
#include <hip/hip_runtime.h>

#define NT 20        // time steps
#define BT 4096      // batch
#define HD 128       // hidden
#define RT 81920     // total rows = K*B = 20*4096
#define RB 64        // rows per block

typedef _Float16 half8 __attribute__((ext_vector_type(8)));
typedef _Float16 half2v __attribute__((ext_vector_type(2)));
typedef float f32x4 __attribute__((ext_vector_type(4)));
typedef float f32x2 __attribute__((ext_vector_type(2)));
typedef unsigned u32x4 __attribute__((ext_vector_type(4)));

#if defined(__has_builtin)
#  if __has_builtin(__builtin_amdgcn_fdot2)
#    define HAVE_FDOT2 1
#  endif
#endif

__device__ __forceinline__ float hsig(float x) {
  return fminf(fmaxf(x * 0.16666667f + 0.5f, 0.0f), 1.0f);
}
__device__ __forceinline__ float htanh(float x) {
  return fminf(fmaxf(x, -1.0f), 1.0f);   // clang emits v_med3_f32
}

__device__ __forceinline__ float dot2(half2v a, half2v b, float c) {
#ifdef HAVE_FDOT2
  return __builtin_amdgcn_fdot2(a, b, c, false);
#else
  return fmaf((float)a[0], (float)b[0], fmaf((float)a[1], (float)b[1], c));
#endif
}

__device__ __forceinline__ half8 ldcvt8(const float* __restrict__ p) {
  f32x4 a = *(const f32x4*)p;
  f32x4 b = *(const f32x4*)(p + 4);
  half8 r;
  r[0] = (_Float16)a[0]; r[1] = (_Float16)a[1];
  r[2] = (_Float16)a[2]; r[3] = (_Float16)a[3];
  r[4] = (_Float16)b[0]; r[5] = (_Float16)b[1];
  r[6] = (_Float16)b[2]; r[7] = (_Float16)b[3];
  return r;
}

// Persistent LSTM decoder, 64 rows/block, 8 waves, launch_bounds (512,2).
// Allocator model from R2-R7: with MFMA the unified budget splits ~50/50
// arch/accum. (512,2) -> 256/wave -> 128 arch / 128 accum. Live set:
// bW 64 + aug 8 + A-frags 20 + addr/fold ~30 = ~122 arch, acc 16 accum
// => first spill-free config with 2 waves/SIMD. Numerics = R5 (verified,
// absmax 3.9e-3). One scheduling change: wave-rotated m-tile order
// mm=(wm+1+j)&3 -- fold lands at j=3 (tile wm) for every wave, with the
// needed A-frags already in registers; waves start each step on
// different tiles.
// Wave w owns hidden slice [16w,16w+16): gate cols 128n+16w+(l&15) are
// lane-local in the mfma 16x16x32 D-layout (col=l&15, row=4*(l>>4)+reg).
// h: LDS f16 double-buffered, XOR-swizzled byte^=(row&7)<<4. c: LDS
// [mm][tid]*16B (conflict-free b128). gi via 5th aug MFMA K-tile.
__global__ __launch_bounds__(512, 2) void decoder_kernel(
    const float* __restrict__ obs, const float* __restrict__ pred,
    const float* __restrict__ Wm1, const float* __restrict__ bm1,
    const float* __restrict__ Wm2, const float* __restrict__ bm2,
    const float* __restrict__ W_ih, const float* __restrict__ W_hh,
    const float* __restrict__ b_ih, const float* __restrict__ b_hh,
    const float* __restrict__ W_out, const float* __restrict__ b_out,
    float* __restrict__ outp)
{
  __shared__ __align__(16) char lds[71168];
  const int tid = threadIdx.x;
  const int w   = tid >> 6;       // wave id 0..7
  const int l   = tid & 63;
  const int l15 = l & 15;
  const int lg  = l >> 4;         // lane group 0..3
  const int wm  = w & 3;          // fold m-tile
  const int wc  = w >> 2;         // fold output column
  const int r0  = blockIdx.x * RB;
  const int b0  = r0 & (BT - 1);

  char* const buf0 = lds;             // h buffer parity 0 (16KB)
  char* const h1l  = lds + 16384;     // parity-1 h buffer; aliases MLP mid acts
  char* const cstl = lds + 32768;     // c state: [mm][tid] f32x4 (32KB)
  char* const obsl = lds + 65536;     // obs staged: [20][64] packed f16x2 (5KB)
  char* const wol  = lds + 70656;     // W_out f16 [2][128] (512B)

  const f32x4 fzero = {0.f, 0.f, 0.f, 0.f};

  const int rdmask = (l15 & 7) << 4;
  const int arow  = l15 * 256;              // A-read row byte
  const int base0 = (16 * lg) ^ rdmask;     // A-read k byte; ao[kt]=(64*kt)^base0
  const int wcol2 = 32 * w + 2 * l15;       // h-write col byte (pre-swizzle)
  const int cb    = tid * 16;               // + mm*8192 in cstl

  // ---- stage W_out (f16), obs (packed f16x2), zero c-state ----
  if (tid < 256) ((_Float16*)wol)[tid] = (_Float16)W_out[tid];
  for (int i = tid; i < NT * RB; i += 512) {
    int t = i >> 6, row = i & 63;
    int tp = (t > 0) ? t - 1 : 0;
    f32x2 xv = *(const f32x2*)(obs + ((size_t)tp * BT + b0 + row) * 2);
    half2v hp; hp[0] = (_Float16)xv[0]; hp[1] = (_Float16)xv[1];
    *(unsigned*)(obsl + (size_t)i * 4) = __builtin_bit_cast(unsigned, hp);
  }
#pragma unroll
  for (int mm = 0; mm < 4; ++mm)
    *(f32x4*)(cstl + mm * 8192 + cb) = fzero;

  // ---------------- Prologue: h0 = MLP(pred) ----------------
  // GEMM1: h1[64x64] = leaky_relu(pred @ Wm1^T + bm1). wave w: m=wm, n=2wc+{0,1}
  {
    half8 a1[4], b1[2][4];
#pragma unroll
    for (int kt = 0; kt < 4; ++kt)
      a1[kt] = ldcvt8(pred + (size_t)(r0 + 16 * wm + l15) * HD + kt * 32 + lg * 8);
#pragma unroll
    for (int j = 0; j < 2; ++j)
#pragma unroll
      for (int kt = 0; kt < 4; ++kt)
        b1[j][kt] = ldcvt8(Wm1 + (l15 + 16 * (2 * wc + j)) * HD + kt * 32 + lg * 8);
    f32x4 acc1[2] = {fzero, fzero};
#pragma unroll
    for (int kt = 0; kt < 4; ++kt)
#pragma unroll
      for (int j = 0; j < 2; ++j)
        acc1[j] = __builtin_amdgcn_mfma_f32_16x16x32_f16(a1[kt], b1[j][kt], acc1[j], 0, 0, 0);
#pragma unroll
    for (int j = 0; j < 2; ++j) {
      int c = l15 + 16 * (2 * wc + j);
      float bb = bm1[c];
#pragma unroll
      for (int reg = 0; reg < 4; ++reg) {
        int row = 16 * wm + 4 * lg + reg;
        float v = acc1[j][reg] + bb;
        v = v >= 0.f ? v : 0.01f * v;
        *(_Float16*)(h1l + row * 128 + ((2 * c) ^ ((row & 7) << 4))) = (_Float16)v;
      }
    }
  }
  __syncthreads();
  // GEMM2: h0[64x128] = h1 @ Wm2^T + bm2 -> buf0. wave w: m=wm, n=4wc+{0..3}
  {
    half8 a2[2], b2[4][2];
#pragma unroll
    for (int kt = 0; kt < 2; ++kt)
      a2[kt] = *(const half8*)(h1l + (16 * wm + l15) * 128 + ((64 * kt + 16 * lg) ^ rdmask));
#pragma unroll
    for (int j = 0; j < 4; ++j)
#pragma unroll
      for (int kt = 0; kt < 2; ++kt)
        b2[j][kt] = ldcvt8(Wm2 + (l15 + 16 * (4 * wc + j)) * 64 + kt * 32 + lg * 8);
    f32x4 acc2[4] = {fzero, fzero, fzero, fzero};
#pragma unroll
    for (int kt = 0; kt < 2; ++kt)
#pragma unroll
      for (int j = 0; j < 4; ++j)
        acc2[j] = __builtin_amdgcn_mfma_f32_16x16x32_f16(a2[kt], b2[j][kt], acc2[j], 0, 0, 0);
#pragma unroll
    for (int j = 0; j < 4; ++j) {
      int c = l15 + 16 * (4 * wc + j);
      float bb = bm2[c];
#pragma unroll
      for (int reg = 0; reg < 4; ++reg) {
        int row = 16 * wm + 4 * lg + reg;
        float v = acc2[j][reg] + bb;
        *(_Float16*)(buf0 + row * 256 + ((2 * c) ^ ((row & 7) << 4))) = (_Float16)v;
      }
    }
  }

  // ---- steady-state per-wave constants ----
  // bW: W_hh fragments (64 VGPR). Aug payload packed: awp=(W_ih[g,0],
  // W_ih[g,1]) f16x2; abp=(b_ih[g]+b_hh[g], 0) f16x2.
  half8 bW[4][4];
  unsigned awp[4], abp[4];
#pragma unroll
  for (int n = 0; n < 4; ++n) {
    int g = 128 * n + 16 * w + l15;
#pragma unroll
    for (int kt = 0; kt < 4; ++kt)
      bW[n][kt] = ldcvt8(W_hh + (size_t)g * HD + kt * 32 + lg * 8);
    half2v t2;
    t2[0] = (_Float16)W_ih[g * 2 + 0];
    t2[1] = (_Float16)W_ih[g * 2 + 1];
    awp[n] = __builtin_bit_cast(unsigned, t2);
    half2v t3;
    t3[0] = (_Float16)(b_ih[g] + b_hh[g]);
    t3[1] = (_Float16)0.0f;
    abp[n] = __builtin_bit_cast(unsigned, t3);
  }
  const float bo = wc ? b_out[1] : b_out[0];

  __syncthreads();  // h0/obs/wol/cst visible; h1l reads done

  // ---------------- 20 recurrent steps ----------------
  for (int t = 0; t < NT; ++t) {
    char* const brd = lds + ((t & 1) << 14);
    char* const bwr = lds + (((t & 1) ^ 1) << 14);

#pragma unroll
    for (int j = 0; j < 4; ++j) {
      const int mm = (wm + 1 + j) & 3;   // rotation: fold tile (mm==wm) at j==3
      // c-state read issued early, consumed after MFMAs
      f32x4 cc = *(const f32x4*)(cstl + mm * 8192 + cb);

      f32x4 acc[4] = {fzero, fzero, fzero, fzero};
      const bool doFold = (j == 3) && (t > 0);
      float p = 0.f;

      __builtin_amdgcn_s_setprio(1);
#pragma unroll
      for (int kt = 0; kt < 5; ++kt) {
        half8 a;
        if (kt < 4) {
          a = *(const half8*)(brd + mm * 4096 + arow + ((64 * kt) ^ base0));
          if (doFold) {
            const half8 wf = *(const half8*)(wol + wc * 256 + kt * 64 + lg * 16);
#pragma unroll
            for (int pp = 0; pp < 4; ++pp) {
              half2v ha; ha[0] = a[2 * pp]; ha[1] = a[2 * pp + 1];
              half2v wa; wa[0] = wf[2 * pp]; wa[1] = wf[2 * pp + 1];
              p = dot2(ha, wa, p);
            }
          }
        } else {
          // K-augmentation A tile: [x0, x1, 1, 0...] on lane group 0
          unsigned xv = *(const unsigned*)(obsl + ((t << 6) + (mm << 4) + l15) * 4);
          unsigned u0 = (lg == 0) ? xv : 0u;
          unsigned u1 = (lg == 0) ? 0x00003C00u : 0u;  // f16 1.0 in elem 2
          u32x4 xu = {u0, u1, 0u, 0u};
          a = __builtin_bit_cast(half8, xu);
        }
#pragma unroll
        for (int n = 0; n < 4; ++n) {
          half8 bfrag;
          if (kt < 4) {
            bfrag = bW[n][kt];
          } else {
            unsigned v0 = (lg == 0) ? awp[n] : 0u;
            unsigned v1 = (lg == 0) ? abp[n] : 0u;
            u32x4 bu = {v0, v1, 0u, 0u};
            bfrag = __builtin_bit_cast(half8, bu);
          }
          acc[n] = __builtin_amdgcn_mfma_f32_16x16x32_f16(a, bfrag, acc[n], 0, 0, 0);
        }
      }
      __builtin_amdgcn_s_setprio(0);

      if (doFold) {
        p += __shfl_xor(p, 16, 64); p += __shfl_xor(p, 32, 64);
        if (l < 16)
          outp[(size_t)(t - 1) * (RT * 2) + (size_t)(r0 + 16 * wm + l) * 2 + wc] = p + bo;
      }

      // fused LSTM update for this m-tile (lane-local)
      f32x4 cn4;
#pragma unroll
      for (int reg = 0; reg < 4; ++reg) {
        float cn = hsig(acc[1][reg]) * cc[reg] + hsig(acc[0][reg]) * htanh(acc[2][reg]);
        cn4[reg] = cn;
        float hn = hsig(acc[3][reg]) * htanh(cn);
        int rr = 4 * lg + reg;
        int wb = rr * 256 + (wcol2 ^ ((rr & 7) << 4));
        *(_Float16*)(bwr + mm * 4096 + wb) = (_Float16)hn;
      }
      *(f32x4*)(cstl + mm * 8192 + cb) = cn4;
    }
    __syncthreads();
  }

  // ---------------- epilogue: final out from h(20) (buf parity 0) ----------------
  {
    float p = 0.f;
#pragma unroll
    for (int kt = 0; kt < 4; ++kt) {
      half8 a = *(const half8*)(buf0 + wm * 4096 + arow + ((64 * kt) ^ base0));
      const half8 wf = *(const half8*)(wol + wc * 256 + kt * 64 + lg * 16);
#pragma unroll
      for (int pp = 0; pp < 4; ++pp) {
        half2v ha; ha[0] = a[2 * pp]; ha[1] = a[2 * pp + 1];
        half2v wa; wa[0] = wf[2 * pp]; wa[1] = wf[2 * pp + 1];
        p = dot2(ha, wa, p);
      }
    }
    p += __shfl_xor(p, 16, 64); p += __shfl_xor(p, 32, 64);
    if (l < 16)
      outp[(size_t)19 * (RT * 2) + (size_t)(r0 + 16 * wm + l) * 2 + wc] = p + bo;
  }
}

extern "C" void kernel_launch(void* const* d_in, const int* in_sizes, int n_in,
                              void* d_out, int out_size, void* d_ws, size_t ws_size,
                              hipStream_t stream) {
  const float* obs   = (const float*)d_in[0];
  const float* pred  = (const float*)d_in[1];
  const float* Wm1   = (const float*)d_in[2];
  const float* bm1   = (const float*)d_in[3];
  const float* Wm2   = (const float*)d_in[4];
  const float* bm2   = (const float*)d_in[5];
  const float* W_ih  = (const float*)d_in[6];
  const float* W_hh  = (const float*)d_in[7];
  const float* b_ih  = (const float*)d_in[8];
  const float* b_hh  = (const float*)d_in[9];
  const float* W_out = (const float*)d_in[10];
  const float* b_out = (const float*)d_in[11];

  decoder_kernel<<<RT / RB, 512, 0, stream>>>(
      obs, pred, Wm1, bm1, Wm2, bm2, W_ih, W_hh, b_ih, b_hh, W_out, b_out,
      (float*)d_out);
}